// Round 14
// baseline (469.359 us; speedup 1.0000x reference)
//
#include <hip/hip_runtime.h>

#define HD 50
#define TT 512
#define BRR 16        // batch rows per block -> 256 blocks = 1/CU
#define TC 32         // x prefetch chunk (timesteps)
#define KS 136        // shorts per A row (272B): [0..49]=h0 | [50..52]=x | 53..63=0 | [64..113]=h1 | 114..135=0

using f16   = _Float16;
using f16x8 = __attribute__((ext_vector_type(8))) f16;
using f32x4 = __attribute__((ext_vector_type(4))) float;

#define LOG2E 1.4426950408889634f

__device__ __forceinline__ short f2h_bits(float f) {
    f16 h = (f16)f;                      // RNE
    return *reinterpret_cast<short*>(&h);
}
__device__ __forceinline__ float h2f(short b) {
    f16 h = *reinterpret_cast<f16*>(&b);
    return (float)h;
}
__device__ __forceinline__ float frcp(float x) { return __builtin_amdgcn_rcpf(x); }
#if __has_builtin(__builtin_amdgcn_exp2f)
__device__ __forceinline__ float fexp2(float x) { return __builtin_amdgcn_exp2f(x); }
#else
__device__ __forceinline__ float fexp2(float x) { return exp2f(x); }
#endif

// Anti-phase wave roles (each SIMD hosts one wave of each group -> matrix pipe
// and trans pipe busy in BOTH half-ticks; m114 co-scheduling):
//   half1: S0 (waves 0-3) MFMA L0(i)      || S1 (waves 4-7) EW -> h1(i-2)
//   bar1
//   half2: S0 EW -> h0(i) + x-duty        || S1 MFMA L1(i-1)  (acc across bar2)
//   bar2
// S0 reads A cols 0..63 (2 chunks, 8 MFMA); S1 reads all 4 chunks (16 MFMA).
// S1's h1 writes (cols 64+) are disjoint from S0's concurrent reads (cols<64).
// Weights pre-scaled by -log2e / +2log2e; fused-rcp EW (5 exp2 + 3 rcp).
__global__ __launch_bounds__(512, 2) void lstm2_anti(
    const float* __restrict__ x,
    const float* __restrict__ Wih0, const float* __restrict__ Whh0,
    const float* __restrict__ bih0, const float* __restrict__ bhh0,
    const float* __restrict__ Wih1, const float* __restrict__ Whh1,
    const float* __restrict__ bih1, const float* __restrict__ bhh1,
    const float* __restrict__ Wfc, const float* __restrict__ bfc,
    float* __restrict__ out)
{
    __shared__ short s_A[2][BRR][KS];
    __shared__ float s_xs[2][BRR][TC * 3];

    const int tid  = threadIdx.x;
    const int wid  = tid >> 6;
    const int lane = tid & 63;
    const int lr   = lane & 15;          // B/D column = unit slot
    const int lq   = lane >> 4;          // k-octet / D row-quad
    const int r0   = blockIdx.x * BRR;

    const bool isS0 = (wid < 4);
    const int  wsub = wid & 3;
    const int  u     = 4 * lr + wsub;    // layer-local unit
    const bool valid = (u < HD);
    const int  wcol  = isS0 ? u : 64 + u;

    // ---- weight B-fragments (f16, pre-scaled), register-resident ----
    // S0: bw[tt][0..1] over k=[h0|x|bias-span]; S1: bw[tt][0..3] over k=[Wih1|-|Whh1|-]
    f16x8 bw[4][4];
    float bvT[4];
    #pragma unroll
    for (int tt = 0; tt < 4; ++tt) {
        const float sc = (tt == 2) ? (2.0f * LOG2E) : (-LOG2E);
        const int g = tt * HD + (valid ? u : 0);
        #pragma unroll
        for (int s = 0; s < 4; ++s) bw[tt][s] = (f16x8)0;
        if (isS0) {
            bvT[tt] = valid ? (bih0[g] + bhh0[g]) * sc : 0.f;
            #pragma unroll
            for (int s = 0; s < 2; ++s) {
                #pragma unroll
                for (int j = 0; j < 8; ++j) {
                    const int k = s*32 + lq*8 + j;
                    float wv = 0.f;
                    if (valid) {
                        if (k < HD) wv = Whh0[g*HD + k];
                        else if (k < HD + 3) wv = Wih0[g*3 + (k - HD)];
                    }
                    bw[tt][s][j] = (f16)(wv * sc);
                }
            }
        } else {
            bvT[tt] = valid ? (bih1[g] + bhh1[g]) * sc : 0.f;
            #pragma unroll
            for (int s = 0; s < 4; ++s) {
                #pragma unroll
                for (int j = 0; j < 8; ++j) {
                    const int k = s*32 + lq*8 + j;
                    float wv = 0.f;
                    if (valid) {
                        if (k < HD) wv = Wih1[g*HD + k];
                        else if (k >= 64 && k < 64 + HD) wv = Whh1[g*HD + (k - 64)];
                    }
                    bw[tt][s][j] = (f16)(wv * sc);
                }
            }
        }
    }

    // ---- per-lane c-state: 4 batch rows (4*lq+j) of this lane's unit ----
    float cst[4] = {0.f, 0.f, 0.f, 0.f};

    // ---- MFMA accumulators carried across a barrier (S0: bar1; S1: bar2) ----
    f32x4 acc[4];
    #pragma unroll
    for (int tt = 0; tt < 4; ++tt) acc[tt] = (f32x4){0, 0, 0, 0};

    // ---- x duty: invalid lanes of S0 waves ----
    bool xduty = false; int xrow = 0, xd = 0;
    if (isS0 && !valid) {
        const int base[4]   = {0, 12, 24, 40};
        const int lstart[4] = {13, 13, 12, 12};
        const int xidx = base[wsub] + (lr - lstart[wsub]) * 4 + lq;
        if (xidx < 48) { xduty = true; xrow = xidx / 3; xd = xidx % 3; }
    }

    // ---- init: zero A buffers, stage x chunk 0, write x(0) into buf0 ----
    for (int q = tid; q < 2 * BRR * KS; q += 512) ((short*)s_A)[q] = 0;
    for (int q = tid; q < BRR * TC * 3; q += 512) {
        const int rr = q / (TC * 3), qq = q % (TC * 3);
        s_xs[0][rr][qq] = x[(size_t)(r0 + rr) * (TT * 3) + qq];
    }
    __syncthreads();
    if (xduty) s_A[0][xrow][HD + xd] = f2h_bits(s_xs[0][xrow][xd]);
    __syncthreads();

    // ================= main loop: TT+2 iters, TWO barriers each =================
    for (int i = 0; i <= TT + 1; ++i) {
        const char* ab = (const char*)&s_A[i & 1][0][0];

        // ---------- half 1: S0 MFMA L0(i)  ||  S1 EW -> h1(i-2) ----------
        if (isS0) {
            if (i < TT) {
                f16x8 a[2];
                #pragma unroll
                for (int s = 0; s < 2; ++s)
                    a[s] = *(const f16x8*)(ab + lr * (2 * KS) + s * 64 + lq * 16);
                #pragma unroll
                for (int tt = 0; tt < 4; ++tt) { const float b = bvT[tt]; acc[tt] = (f32x4){b, b, b, b}; }
                #pragma unroll
                for (int s = 0; s < 2; ++s) {
                    #pragma unroll
                    for (int tt = 0; tt < 4; ++tt)
                        acc[tt] = __builtin_amdgcn_mfma_f32_16x16x32_f16(a[s], bw[tt][s], acc[tt], 0, 0, 0);
                }
            }
        } else {
            if (valid && i >= 2) {                 // EW of acc (gates L1(i-2)) -> h1(i-2) into buf[i&1]
                #pragma unroll
                for (int j = 0; j < 4; ++j) {
                    const float ei = fexp2(acc[0][j]);
                    const float ef = fexp2(acc[1][j]);
                    const float eg = fexp2(acc[2][j]);
                    const float eo = fexp2(acc[3][j]);
                    const float ig = (eg - 1.0f) * frcp((eg + 1.0f) * (1.0f + ei));
                    const float fv = frcp(1.0f + ef);
                    const float c  = fv * cst[j] + ig;
                    cst[j] = c;
                    const float ec = fexp2(c * (2.0f * LOG2E));
                    const float h  = (ec - 1.0f) * frcp((ec + 1.0f) * (1.0f + eo));
                    s_A[i & 1][lq * 4 + j][wcol] = f2h_bits(h);
                }
            }
        }
        __syncthreads();                            // bar1

        // ---------- half 2: S0 EW -> h0(i) + x-duty  ||  S1 MFMA L1(i-1) ----------
        if (isS0) {
            if (valid && i < TT) {
                #pragma unroll
                for (int j = 0; j < 4; ++j) {
                    const float ei = fexp2(acc[0][j]);
                    const float ef = fexp2(acc[1][j]);
                    const float eg = fexp2(acc[2][j]);
                    const float eo = fexp2(acc[3][j]);
                    const float ig = (eg - 1.0f) * frcp((eg + 1.0f) * (1.0f + ei));
                    const float fv = frcp(1.0f + ef);
                    const float c  = fv * cst[j] + ig;
                    cst[j] = c;
                    const float ec = fexp2(c * (2.0f * LOG2E));
                    const float h  = (ec - 1.0f) * frcp((ec + 1.0f) * (1.0f + eo));
                    s_A[(i + 1) & 1][lq * 4 + j][wcol] = f2h_bits(h);
                }
            }
            if (xduty && (i + 1) < TT) {            // x(i+1) -> buf[(i+1)&1]
                const int tn = i + 1;
                s_A[(i + 1) & 1][xrow][HD + xd] =
                    f2h_bits(s_xs[(tn / TC) & 1][xrow][(tn % TC) * 3 + xd]);
            }
        } else {
            if (i >= 1 && i <= TT) {                // gates L1(i-1) from A(i) = [h0(i-1)|x|h1(i-2)]
                f16x8 a[4];
                #pragma unroll
                for (int s = 0; s < 4; ++s)
                    a[s] = *(const f16x8*)(ab + lr * (2 * KS) + s * 64 + lq * 16);
                #pragma unroll
                for (int tt = 0; tt < 4; ++tt) { const float b = bvT[tt]; acc[tt] = (f32x4){b, b, b, b}; }
                #pragma unroll
                for (int s = 0; s < 4; ++s) {
                    #pragma unroll
                    for (int tt = 0; tt < 4; ++tt)
                        acc[tt] = __builtin_amdgcn_mfma_f32_16x16x32_f16(a[s], bw[tt][s], acc[tt], 0, 0, 0);
                }
            }
        }
        {
            const int t2s = i + 2;                  // stage next x chunk 2 ticks ahead
            if (t2s < TT && (t2s % TC) == 0) {
                const int cb = (t2s / TC) & 1;
                for (int q = tid; q < BRR * TC * 3; q += 512) {
                    const int rr = q / (TC * 3), qq = q % (TC * 3);
                    s_xs[cb][rr][qq] = x[(size_t)(r0 + rr) * (TT * 3) + (size_t)t2s * 3 + qq];
                }
            }
        }
        __syncthreads();                            // bar2
    }

    // ---- FC epilogue: h1(TT-1) written at iter TT+1 into buf[(TT+1)&1]=1, cols 64..113 ----
    if (tid < BRR * 7) {
        const int r = tid / 7, o = tid % 7;
        float acc2 = bfc[o];
        #pragma unroll
        for (int uu = 0; uu < HD; ++uu)
            acc2 += h2f(s_A[1][r][64 + uu]) * Wfc[o * HD + uu];
        out[(size_t)(r0 + r) * 7 + o] = acc2;
    }
}

extern "C" void kernel_launch(void* const* d_in, const int* in_sizes, int n_in,
                              void* d_out, int out_size, void* d_ws, size_t ws_size,
                              hipStream_t stream) {
    const float* xp    = (const float*)d_in[0];
    const float* Wih0  = (const float*)d_in[1];
    const float* Whh0  = (const float*)d_in[2];
    const float* bih0  = (const float*)d_in[3];
    const float* bhh0  = (const float*)d_in[4];
    const float* Wih1  = (const float*)d_in[5];
    const float* Whh1  = (const float*)d_in[6];
    const float* bih1  = (const float*)d_in[7];
    const float* bhh1  = (const float*)d_in[8];
    const float* Wfc   = (const float*)d_in[9];
    const float* bfc   = (const float*)d_in[10];
    float* outp = (float*)d_out;

    const int B = in_sizes[0] / (TT * 3);   // 4096
    const int grid = B / BRR;               // 256 blocks, 1 per CU

    lstm2_anti<<<grid, 512, 0, stream>>>(
        xp, Wih0, Whh0, bih0, bhh0, Wih1, Whh1, bih1, bhh1, Wfc, bfc, outp);
}